// Round 1
// baseline (906.197 us; speedup 1.0000x reference)
//
#include <hip/hip_runtime.h>
#include <hip/hip_fp16.h>

#define SEQ 256
#define BATCH 4096
#define DD 100            // D = 2*hidden
#define FSTRIDE 104       // f16 elems per LDS row; 104*2=208 B -> 16B-aligned rows

__device__ __forceinline__ float fast_tanh(float x) {
    // tanh(x) = sign(x) * (1 - e^(-2|x|)) / (1 + e^(-2|x|)); e in (0,1] -> always stable
    float ax = fabsf(x);
    float e  = __expf(-2.0f * ax);
    float t  = (1.0f - e) * __builtin_amdgcn_rcpf(1.0f + e);
    return copysignf(t, x);
}

__global__ __launch_bounds__(256, 2)
void fused_sent_attn(const float* __restrict__ f,     // [SEQ, BATCH, DD]
                     const float* __restrict__ W,     // [DD, DD] row-major (d, e)
                     const float* __restrict__ bias,  // [DD]
                     const float* __restrict__ cw,    // [DD]
                     float* __restrict__ out)         // pooled [BATCH, DD]
{
    __shared__ __half fs[SEQ * FSTRIDE];
    __shared__ float  sc[SEQ];     // attn weights (written post-softmax)
    __shared__ float  red[8];

    const int b   = blockIdx.x;
    const int tid = threadIdx.x;
    const int lane = tid & 63;
    const int wid  = tid >> 6;

    // ---- stage f[:, b, :] -> LDS (f16), coalesced float4 loads ----
    // 256 rows * 25 float4/row = 6400 loads, 25 per thread
    for (int i = tid; i < SEQ * 25; i += 256) {
        const int row = i / 25;
        const int c4  = i % 25;
        const float4 v = *reinterpret_cast<const float4*>(
            f + (size_t)row * (BATCH * DD) + (size_t)b * DD + c4 * 4);
        __half2* dst = reinterpret_cast<__half2*>(fs + row * FSTRIDE + c4 * 4);
        dst[0] = __half2(__float2half(v.x), __float2half(v.y));
        dst[1] = __half2(__float2half(v.z), __float2half(v.w));
    }
    __syncthreads();

    // ---- thread t owns row s = t: pull row into registers (fp32) ----
    float fr[DD];
    #pragma unroll
    for (int d = 0; d < DD; ++d)
        fr[d] = __half2float(fs[tid * FSTRIDE + d]);

    // ---- u = tanh(fr @ W + bias); score = tanh(u . cw) ----
    // e-blocks of 4: 4 independent accumulators (FMA-latency ILP),
    // W rows give 4 consecutive e per float4 (uniform address -> s_load)
    float sacc = 0.0f;
    for (int e0 = 0; e0 < DD; e0 += 4) {
        const float4 bi = *reinterpret_cast<const float4*>(bias + e0);
        float a0 = bi.x, a1 = bi.y, a2 = bi.z, a3 = bi.w;
        #pragma unroll
        for (int d = 0; d < DD; ++d) {
            const float4 w4 = *reinterpret_cast<const float4*>(W + d * DD + e0);
            a0 = fmaf(fr[d], w4.x, a0);
            a1 = fmaf(fr[d], w4.y, a1);
            a2 = fmaf(fr[d], w4.z, a2);
            a3 = fmaf(fr[d], w4.w, a3);
        }
        const float4 c4 = *reinterpret_cast<const float4*>(cw + e0);
        sacc = fmaf(fast_tanh(a0), c4.x, sacc);
        sacc = fmaf(fast_tanh(a1), c4.y, sacc);
        sacc = fmaf(fast_tanh(a2), c4.z, sacc);
        sacc = fmaf(fast_tanh(a3), c4.w, sacc);
    }
    const float score = fast_tanh(sacc);

    // ---- softmax over s (256 values, one per thread) ----
    float m = score;
    #pragma unroll
    for (int off = 32; off >= 1; off >>= 1)
        m = fmaxf(m, __shfl_xor(m, off));
    if (lane == 0) red[wid] = m;
    __syncthreads();
    m = fmaxf(fmaxf(red[0], red[1]), fmaxf(red[2], red[3]));

    const float p = __expf(score - m);
    float ssum = p;
    #pragma unroll
    for (int off = 32; off >= 1; off >>= 1)
        ssum += __shfl_xor(ssum, off);
    if (lane == 0) red[4 + wid] = ssum;
    __syncthreads();
    const float denom = red[4] + red[5] + red[6] + red[7];
    const float attn = p / denom;

    sc[tid] = attn;
    __syncthreads();

    // ---- pooled[d] = sum_s attn[s] * f[s, b, d] ----
    if (tid < DD) {
        float acc = 0.0f;
        #pragma unroll 8
        for (int s = 0; s < SEQ; ++s)
            acc = fmaf(sc[s], __half2float(fs[s * FSTRIDE + tid]), acc);
        out[(size_t)b * DD + tid] = acc;
    }
}

__global__ void copy_h(const float* __restrict__ src, float* __restrict__ dst, int n4) {
    const int i = blockIdx.x * blockDim.x + threadIdx.x;
    if (i < n4)
        reinterpret_cast<float4*>(dst)[i] = reinterpret_cast<const float4*>(src)[i];
}

extern "C" void kernel_launch(void* const* d_in, const int* in_sizes, int n_in,
                              void* d_out, int out_size, void* d_ws, size_t ws_size,
                              hipStream_t stream) {
    const float* f    = (const float*)d_in[0];   // [256, 4096, 100]
    const float* h    = (const float*)d_in[1];   // [2, 4096, 50]
    const float* W    = (const float*)d_in[2];   // [100, 100]
    const float* bias = (const float*)d_in[3];   // [1, 100]
    const float* cw   = (const float*)d_in[4];   // [100, 1]
    float* out = (float*)d_out;                  // [pooled 409600 | h 409600]

    fused_sent_attn<<<BATCH, 256, 0, stream>>>(f, W, bias, cw, out);

    const int nh = 2 * BATCH * (DD / 2);         // 409600 floats
    const int n4 = nh / 4;                       // 102400 float4
    copy_h<<<(n4 + 255) / 256, 256, 0, stream>>>(h, out + (size_t)BATCH * DD, n4);
}

// Round 2
// 188.075 us; speedup vs baseline: 4.8183x; 4.8183x over previous
//
#include <hip/hip_runtime.h>
#include <hip/hip_bf16.h>

#define SEQ 256
#define BATCH 4096
#define DD 100            // D = 2*hidden
#define SB (BATCH * DD)   // stride between seq steps, in floats

typedef __attribute__((ext_vector_type(8))) short bf16x8;
typedef __attribute__((ext_vector_type(4))) float f32x4;

__device__ __forceinline__ short f2bf(float x) {
    __hip_bfloat16 h = __float2bfloat16(x);
    return *reinterpret_cast<short*>(&h);
}
__device__ __forceinline__ float bf2f(short s) {
    unsigned int u = ((unsigned int)(unsigned short)s) << 16;
    return __builtin_bit_cast(float, u);
}

__device__ __forceinline__ float fast_tanh(float x) {
    float ax = fabsf(x);
    float e  = __expf(-2.0f * ax);
    float t  = (1.0f - e) * __builtin_amdgcn_rcpf(1.0f + e);
    return copysignf(t, x);
}

// ---- prep: pack W [DD x DD] fp32 into MFMA B-fragments, bf16, zero-padded ----
// frag (n,t): B-tile cols [16n,16n+16), k [32t,32t+32). lane l holds
// col = 16n + (l&15), k = 32t + 8*(l>>4) + e  (e = 0..7)  -> one uint4 per lane.
__global__ void prep_wfrag(const float* __restrict__ W, uint4* __restrict__ wsf) {
    const int idx = blockIdx.x * 256 + threadIdx.x;   // 0 .. 1791
    if (idx >= 28 * 64) return;
    const int l  = idx & 63;
    const int ft = idx >> 6;          // 0..27 = n*4 + t
    const int t  = ft & 3;
    const int n  = ft >> 2;
    const int col   = 16 * n + (l & 15);
    const int kbase = 32 * t + 8 * (l >> 4);
    unsigned short v[8];
    #pragma unroll
    for (int e = 0; e < 8; ++e) {
        const int k = kbase + e;
        const float w = (col < DD && k < DD) ? W[k * DD + col] : 0.0f;
        v[e] = (unsigned short)f2bf(w);
    }
    uint4 u;
    u.x = (unsigned)v[0] | ((unsigned)v[1] << 16);
    u.y = (unsigned)v[2] | ((unsigned)v[3] << 16);
    u.z = (unsigned)v[4] | ((unsigned)v[5] << 16);
    u.w = (unsigned)v[6] | ((unsigned)v[7] << 16);
    wsf[ft * 64 + l] = u;
}

__global__ __launch_bounds__(256, 3)
void fused_sent_attn(const float* __restrict__ f,     // [SEQ, BATCH, DD]
                     const uint4* __restrict__ wsf,   // packed W frags
                     const float* __restrict__ bias,  // [DD]
                     const float* __restrict__ cw,    // [DD]
                     float* __restrict__ out)         // pooled [BATCH, DD]
{
    __shared__ float sc[SEQ];
    __shared__ float pool[4][DD];
    __shared__ float red[8];

    const int b    = blockIdx.x;
    const int tid  = threadIdx.x;
    const int lane = tid & 63;
    const int wid  = tid >> 6;
    const int lr   = lane & 15;    // A-row-in-tile / B,C-col-in-tile
    const int g    = lane >> 4;    // k-group
    const int wave_base = wid * 64;

    // ---- A-fragments: wave's 64 rows of f, bf16, K padded 100 -> 128 ----
    bf16x8 a[4][4];
    #pragma unroll
    for (int m = 0; m < 4; ++m) {
        const float* frow = f + (size_t)(wave_base + 16 * m + lr) * SB + b * DD;
        #pragma unroll
        for (int t = 0; t < 4; ++t) {
            bf16x8 av = {0, 0, 0, 0, 0, 0, 0, 0};
            if (t < 3) {
                const int k0 = 32 * t + 8 * g;
                const float4 v0 = *reinterpret_cast<const float4*>(frow + k0);
                const float4 v1 = *reinterpret_cast<const float4*>(frow + k0 + 4);
                av[0] = f2bf(v0.x); av[1] = f2bf(v0.y);
                av[2] = f2bf(v0.z); av[3] = f2bf(v0.w);
                av[4] = f2bf(v1.x); av[5] = f2bf(v1.y);
                av[6] = f2bf(v1.z); av[7] = f2bf(v1.w);
            } else if (g == 0) {   // k 96..99 valid, 100..103 zero
                const float4 v0 = *reinterpret_cast<const float4*>(frow + 96);
                av[0] = f2bf(v0.x); av[1] = f2bf(v0.y);
                av[2] = f2bf(v0.z); av[3] = f2bf(v0.w);
            }
            a[m][t] = av;
        }
    }

    // ---- U = tanh(F W + bias); score_part = sum_e tanh(u) * cw[e] ----
    float scp[4][4] = {{0.0f}};
    #pragma unroll
    for (int n = 0; n < 7; ++n) {
        const int coln = 16 * n + lr;
        const float bias_v = (coln < DD) ? bias[coln] : 0.0f;
        const float cw_v   = (coln < DD) ? cw[coln]   : 0.0f;
        bf16x8 bfr[4];
        #pragma unroll
        for (int t = 0; t < 4; ++t)
            bfr[t] = *reinterpret_cast<const bf16x8*>(&wsf[(n * 4 + t) * 64 + lane]);
        f32x4 acc[4];
        #pragma unroll
        for (int m = 0; m < 4; ++m)
            acc[m] = (f32x4){bias_v, bias_v, bias_v, bias_v};
        #pragma unroll
        for (int t = 0; t < 4; ++t)
            #pragma unroll
            for (int m = 0; m < 4; ++m)
                acc[m] = __builtin_amdgcn_mfma_f32_16x16x32_bf16(a[m][t], bfr[t], acc[m], 0, 0, 0);
        #pragma unroll
        for (int m = 0; m < 4; ++m)
            #pragma unroll
            for (int r = 0; r < 4; ++r)
                scp[m][r] = fmaf(fast_tanh(acc[m][r]), cw_v, scp[m][r]);
    }

    // ---- reduce over cols (16 lanes of lr), final tanh, publish scores ----
    #pragma unroll
    for (int m = 0; m < 4; ++m)
        #pragma unroll
        for (int r = 0; r < 4; ++r) {
            float v = scp[m][r];
            v += __shfl_xor(v, 1);
            v += __shfl_xor(v, 2);
            v += __shfl_xor(v, 4);
            v += __shfl_xor(v, 8);
            scp[m][r] = fast_tanh(v);       // score for row 16m + 4g + r
        }
    if (lr == 0) {
        #pragma unroll
        for (int m = 0; m < 4; ++m)
            #pragma unroll
            for (int r = 0; r < 4; ++r)
                sc[wave_base + 16 * m + 4 * g + r] = scp[m][r];
    }
    __syncthreads();

    // ---- softmax over s = 256 (one value per thread) ----
    const float score = sc[tid];
    float mx = score;
    #pragma unroll
    for (int off = 32; off >= 1; off >>= 1)
        mx = fmaxf(mx, __shfl_xor(mx, off));
    if (lane == 0) red[wid] = mx;
    __syncthreads();
    mx = fmaxf(fmaxf(red[0], red[1]), fmaxf(red[2], red[3]));

    const float p = __expf(score - mx);
    float ssum = p;
    #pragma unroll
    for (int off = 32; off >= 1; off >>= 1)
        ssum += __shfl_xor(ssum, off);
    if (lane == 0) red[4 + wid] = ssum;
    __syncthreads();
    const float denom = red[4] + red[5] + red[6] + red[7];
    sc[tid] = p / denom;                    // attn[s]
    __syncthreads();

    // ---- pooled[d] = sum_s attn[s] * f[s,d]  from register A-frags ----
    float aw[4];
    #pragma unroll
    for (int m = 0; m < 4; ++m)
        aw[m] = sc[wave_base + 16 * m + lr];

    float pp[4][8];
    #pragma unroll
    for (int t = 0; t < 4; ++t)
        #pragma unroll
        for (int e = 0; e < 8; ++e) {
            float v = 0.0f;
            #pragma unroll
            for (int m = 0; m < 4; ++m)
                v = fmaf(aw[m], bf2f(a[m][t][e]), v);
            v += __shfl_xor(v, 1);
            v += __shfl_xor(v, 2);
            v += __shfl_xor(v, 4);
            v += __shfl_xor(v, 8);
            pp[t][e] = v;                  // sum over this wave's 64 rows
        }
    if (lr == 0) {
        #pragma unroll
        for (int t = 0; t < 4; ++t)
            #pragma unroll
            for (int e = 0; e < 8; ++e) {
                const int d = 32 * t + 8 * g + e;
                if (d < DD) pool[wid][d] = pp[t][e];
            }
    }
    __syncthreads();

    if (tid < DD)
        out[(size_t)b * DD + tid] =
            pool[0][tid] + pool[1][tid] + pool[2][tid] + pool[3][tid];
}

__global__ void copy_h(const float* __restrict__ src, float* __restrict__ dst, int n4) {
    const int i = blockIdx.x * blockDim.x + threadIdx.x;
    if (i < n4)
        reinterpret_cast<float4*>(dst)[i] = reinterpret_cast<const float4*>(src)[i];
}

extern "C" void kernel_launch(void* const* d_in, const int* in_sizes, int n_in,
                              void* d_out, int out_size, void* d_ws, size_t ws_size,
                              hipStream_t stream) {
    const float* f    = (const float*)d_in[0];   // [256, 4096, 100]
    const float* h    = (const float*)d_in[1];   // [2, 4096, 50]
    const float* W    = (const float*)d_in[2];   // [100, 100]
    const float* bias = (const float*)d_in[3];   // [1, 100]
    const float* cw   = (const float*)d_in[4];   // [100, 1]
    float* out = (float*)d_out;                  // [pooled 409600 | h 409600]

    uint4* wsf = (uint4*)d_ws;                   // 28 * 64 * 16 B = 28672 B

    prep_wfrag<<<7, 256, 0, stream>>>(W, wsf);
    fused_sent_attn<<<BATCH, 256, 0, stream>>>(f, wsf, bias, cw, out);

    const int nh = 2 * BATCH * (DD / 2);         // 409600 floats
    const int n4 = nh / 4;
    copy_h<<<(n4 + 255) / 256, 256, 0, stream>>>(h, out + (size_t)BATCH * DD, n4);
}